// Round 17
// baseline (297.933 us; speedup 1.0000x reference)
//
#include <hip/hip_runtime.h>
#include <hip/hip_bf16.h>
#include <math.h>

// Problem constants
#define B_    2
#define T_    2048
#define HID_  2048
#define H_    16
#define DK_   64
#define DV_   128
#define CC    16
#define NCHUNK (T_/CC)     // 128
#define NSEG  16           // segments per (b,h); 8 chunks each
#define M_    (B_*T_)      // 4096
#define SCALE_ 0.125f      // DK^-0.5

typedef __attribute__((ext_vector_type(8))) __bf16 bf16x8;
typedef __attribute__((ext_vector_type(8))) unsigned short u16x8;
typedef __attribute__((ext_vector_type(4))) float f32x4;

__device__ __forceinline__ unsigned short f2bf(float f) {
  unsigned int u = __float_as_uint(f);
  u += 0x7fff + ((u >> 16) & 1);   // RNE
  return (unsigned short)(u >> 16);
}
__device__ __forceinline__ float bf2f(unsigned short u) {
  return __uint_as_float(((unsigned int)u) << 16);
}

typedef const __attribute__((address_space(1))) void* as1cv;
typedef __attribute__((address_space(3))) void* as3v;
__device__ __forceinline__ void gload16(const void* g, void* l) {
  __builtin_amdgcn_global_load_lds((as1cv)g, (as3v)l, 16, 0, 0);
}

// ------ fused prep: lr gate FIRST, then x convert, then LDS-free column transposes --------
// [0,1024): lr gate (4 rows/block); [1024,3072): x convert; [3072,4096): transpose 64kx256n
__global__ __launch_bounds__(256) void prep_kernel(const float* __restrict__ x,
                                                   unsigned short* __restrict__ xb,
                                                   const float* __restrict__ Wq,
                                                   const float* __restrict__ Wk,
                                                   const float* __restrict__ Wv,
                                                   const float* __restrict__ Wg,
                                                   const float* __restrict__ Wo,
                                                   unsigned short* __restrict__ WqkT,
                                                   unsigned short* __restrict__ WvgT,
                                                   unsigned short* __restrict__ WoT,
                                                   const float* __restrict__ w1,
                                                   const float* __restrict__ w2,
                                                   const float* __restrict__ bias,
                                                   float* __restrict__ gkout) {
  const int t = threadIdx.x;
  int id = blockIdx.x;
  if (id < 1024) {
    // low-rank gate: gk = log_sigmoid(x@W1@W2 + b)/16, 4 rows per block
    __shared__ float part[4][4][17];
    __shared__ float t1s[4][16];
    const int row0 = id * 4;
    const int r    = t >> 6;
    const int lane = t & 63;
    const int j    = lane & 15;
    const int p    = lane >> 4;
    const float* xr = x + (size_t)(row0 + r) * HID_;
    float acc = 0.f;
    const int k0 = p * 512;
    for (int kk = k0; kk < k0 + 512; kk += 4) {
      float4 xv = *reinterpret_cast<const float4*>(&xr[kk]);
      acc = fmaf(xv.x, w1[(kk+0)*16 + j], acc);
      acc = fmaf(xv.y, w1[(kk+1)*16 + j], acc);
      acc = fmaf(xv.z, w1[(kk+2)*16 + j], acc);
      acc = fmaf(xv.w, w1[(kk+3)*16 + j], acc);
    }
    part[r][p][j] = acc;
    __syncthreads();
    if (t < 64) {
      int rr = t >> 4, jj = t & 15;
      t1s[rr][jj] = part[rr][0][jj] + part[rr][1][jj] + part[rr][2][jj] + part[rr][3][jj];
    }
    __syncthreads();
    #pragma unroll
    for (int i = 0; i < 4; ++i) {
      int n = t + i * 256;
      float b0 = bias[n];
      float a0 = b0, a1 = b0, a2 = b0, a3 = b0;
      #pragma unroll
      for (int jj = 0; jj < 16; ++jj) {
        float wv = w2[jj * 1024 + n];
        a0 = fmaf(t1s[0][jj], wv, a0);
        a1 = fmaf(t1s[1][jj], wv, a1);
        a2 = fmaf(t1s[2][jj], wv, a2);
        a3 = fmaf(t1s[3][jj], wv, a3);
      }
      gkout[(size_t)(row0+0)*1024 + n] = (fminf(a0,0.f) - log1pf(expf(-fabsf(a0)))) * (1.f/16.f);
      gkout[(size_t)(row0+1)*1024 + n] = (fminf(a1,0.f) - log1pf(expf(-fabsf(a1)))) * (1.f/16.f);
      gkout[(size_t)(row0+2)*1024 + n] = (fminf(a2,0.f) - log1pf(expf(-fabsf(a2)))) * (1.f/16.f);
      gkout[(size_t)(row0+3)*1024 + n] = (fminf(a3,0.f) - log1pf(expf(-fabsf(a3)))) * (1.f/16.f);
    }
    return;
  }
  id -= 1024;
  if (id < 2048) {
    const float4* x4 = reinterpret_cast<const float4*>(x);
    ushort4* o4 = reinterpret_cast<ushort4*>(xb);
    const int base = id * 1024 + t;
    float4 f0 = x4[base];
    float4 f1 = x4[base + 256];
    float4 f2 = x4[base + 512];
    float4 f3 = x4[base + 768];
    ushort4 u0 = {f2bf(f0.x), f2bf(f0.y), f2bf(f0.z), f2bf(f0.w)};
    ushort4 u1 = {f2bf(f1.x), f2bf(f1.y), f2bf(f1.z), f2bf(f1.w)};
    ushort4 u2 = {f2bf(f2.x), f2bf(f2.y), f2bf(f2.z), f2bf(f2.w)};
    ushort4 u3 = {f2bf(f3.x), f2bf(f3.y), f2bf(f3.z), f2bf(f3.w)};
    o4[base] = u0; o4[base + 256] = u1; o4[base + 512] = u2; o4[base + 768] = u3;
    return;
  }
  id -= 2048;
  // LDS-free transpose: block = 64 k-rows x 256 n-cols; thread owns column n.
  const float* in; unsigned short* out; int N;
  if (id < 128)       { in = Wq; out = WqkT;                         N = 1024; }
  else if (id < 256)  { in = Wk; out = WqkT + (size_t)1024*2048;     N = 1024; id -= 128; }
  else if (id < 512)  { in = Wv; out = WvgT;                         N = 2048; id -= 256; }
  else if (id < 768)  { in = Wg; out = WvgT + (size_t)2048*2048;     N = 2048; id -= 512; }
  else                { in = Wo; out = WoT;                          N = 2048; id -= 768; }
  const int nx = N >> 8;                 // n-tiles of 256
  const int n  = (id % nx) * 256 + t;    // this thread's column
  const int k0 = (id / nx) * 64;
  #pragma unroll
  for (int c = 0; c < 8; ++c) {
    u16x8 u;
    #pragma unroll
    for (int r = 0; r < 8; ++r)
      u[r] = f2bf(in[(size_t)(k0 + c*8 + r) * N + n]);   // wave reads 1KB contiguous per row
    *reinterpret_cast<u16x8*>(&out[(size_t)n * 2048 + k0 + c*8]) = u;
  }
}

// ---------------- 256x256 bf16 MFMA GEMM — compiler-scheduled, 3-barrier ledger -----------
template<bool OBF>
__global__ __launch_bounds__(512, 2) void gemm256(const unsigned short* __restrict__ A,
                                                  const unsigned short* __restrict__ Bt,
                                                  void* __restrict__ Cv,
                                                  int M, int N, int K) {
  __shared__ char ldsb[131072];
  const int t    = threadIdx.x;
  const int lane = t & 63;
  const int wid  = t >> 6;
  const int wr   = wid >> 2;        // 0..1
  const int wc   = wid & 3;         // 0..3
  const int lr   = lane & 15;
  const int lk   = lane >> 4;       // 0..3
  int flat = blockIdx.y * gridDim.x + blockIdx.x;
  if (gridDim.x * gridDim.y == 256) flat = (flat & 7) * 32 + (flat >> 3);  // XCD-chunked
  const int row0 = (flat / gridDim.x) * 256;
  const int col0 = (flat % gridDim.x) * 256;
  const int NKT  = K >> 6;
  const size_t K2 = (size_t)K * 2;

  const int r_s  = t >> 2;
  const int kx_s = ((t & 3) * 16) ^ (((t >> 5) & 1) << 5);

  const int ha = wr;
  const int hb = wc >> 1;
  const int rbl = (wc & 1) * 64;

  f32x4 acc[8][4];
  #pragma unroll
  for (int m = 0; m < 8; ++m)
    #pragma unroll
    for (int n = 0; n < 4; ++n) acc[m][n] = (f32x4){0.f, 0.f, 0.f, 0.f};

  auto stage_half = [&](int p, int o, int h, int kt) {
    const char* src = o ? (const char*)Bt : (const char*)A;
    const int R0 = (o ? col0 : row0) + h * 128;
    const char* g = src + (size_t)(R0 + r_s) * K2 + (size_t)kt * 128 + kx_s;
    char* l = ldsb + ((((p << 1) | o) << 1 | h) << 14) + t * 16;
    gload16(g, l);
    gload16(g + 64, l + 8192);
  };
  auto lda = [&](int p, int mf, int ks) -> bf16x8 {
    int r = mf * 16 + lr;
    int a = ((((p << 1) | 0) << 1 | ha) << 14) + ks * 8192 + r * 64 + lk * 16;
    a ^= ((r >> 3) & 1) << 5;
    return *(const bf16x8*)(ldsb + a);
  };
  auto ldb = [&](int p, int nf, int ks) -> bf16x8 {
    int r = rbl + nf * 16 + lr;
    int a = ((((p << 1) | 1) << 1 | hb) << 14) + ks * 8192 + r * 64 + lk * 16;
    a ^= ((r >> 3) & 1) << 5;
    return *(const bf16x8*)(ldsb + a);
  };

  stage_half(0, 1, 0, 0); stage_half(0, 1, 1, 0);
  stage_half(0, 0, 0, 0); stage_half(0, 0, 1, 0);
  if (1 < NKT) {
    stage_half(1, 1, 0, 1); stage_half(1, 1, 1, 1);
    stage_half(1, 0, 0, 1); stage_half(1, 0, 1, 1);
  }
  asm volatile("s_waitcnt vmcnt(8)" ::: "memory");
  __builtin_amdgcn_s_barrier();
  __builtin_amdgcn_sched_barrier(0);

  bf16x8 fa[4][2], fb[2][2], fb2[2][2];

  for (int kt = 0; kt < NKT; ++kt) {
    const int p = kt & 1;
    const bool st = (kt + 2 < NKT);
    #pragma unroll
    for (int m = 0; m < 4; ++m) { fa[m][0] = lda(p, m, 0); fa[m][1] = lda(p, m, 1); }
    #pragma unroll
    for (int n = 0; n < 2; ++n) { fb[n][0] = ldb(p, n, 0); fb[n][1] = ldb(p, n, 1); }
    #pragma unroll
    for (int n = 0; n < 2; ++n) { fb2[n][0] = ldb(p, n + 2, 0); fb2[n][1] = ldb(p, n + 2, 1); }
    __builtin_amdgcn_s_setprio(1);
    #pragma unroll
    for (int m = 0; m < 4; ++m)
      #pragma unroll
      for (int n = 0; n < 2; ++n) {
        acc[m][n] = __builtin_amdgcn_mfma_f32_16x16x32_bf16(fa[m][0], fb[n][0], acc[m][n], 0, 0, 0);
        acc[m][n] = __builtin_amdgcn_mfma_f32_16x16x32_bf16(fa[m][1], fb[n][1], acc[m][n], 0, 0, 0);
      }
    #pragma unroll
    for (int m = 0; m < 4; ++m)
      #pragma unroll
      for (int n = 0; n < 2; ++n) {
        acc[m][n+2] = __builtin_amdgcn_mfma_f32_16x16x32_bf16(fa[m][0], fb2[n][0], acc[m][n+2], 0, 0, 0);
        acc[m][n+2] = __builtin_amdgcn_mfma_f32_16x16x32_bf16(fa[m][1], fb2[n][1], acc[m][n+2], 0, 0, 0);
      }
    __builtin_amdgcn_s_setprio(0);
    __builtin_amdgcn_sched_barrier(0);
    __builtin_amdgcn_s_barrier();   // B1: all waves done reading B(p) + fa0-3
    __builtin_amdgcn_sched_barrier(0);
    if (st) { stage_half(p, 1, 0, kt + 2); stage_half(p, 1, 1, kt + 2); }  // restage B(p)
    #pragma unroll
    for (int m = 0; m < 4; ++m) { fa[m][0] = lda(p, m + 4, 0); fa[m][1] = lda(p, m + 4, 1); }
    __builtin_amdgcn_s_setprio(1);
    #pragma unroll
    for (int m = 0; m < 4; ++m)
      #pragma unroll
      for (int n = 0; n < 2; ++n) {
        acc[m+4][n] = __builtin_amdgcn_mfma_f32_16x16x32_bf16(fa[m][0], fb[n][0], acc[m+4][n], 0, 0, 0);
        acc[m+4][n] = __builtin_amdgcn_mfma_f32_16x16x32_bf16(fa[m][1], fb[n][1], acc[m+4][n], 0, 0, 0);
      }
    #pragma unroll
    for (int m = 0; m < 4; ++m)
      #pragma unroll
      for (int n = 0; n < 2; ++n) {
        acc[m+4][n+2] = __builtin_amdgcn_mfma_f32_16x16x32_bf16(fa[m][0], fb2[n][0], acc[m+4][n+2], 0, 0, 0);
        acc[m+4][n+2] = __builtin_amdgcn_mfma_f32_16x16x32_bf16(fa[m][1], fb2[n][1], acc[m+4][n+2], 0, 0, 0);
      }
    __builtin_amdgcn_s_setprio(0);
    __builtin_amdgcn_sched_barrier(0);
    __builtin_amdgcn_s_barrier();   // B2: all waves done reading A(p)
    __builtin_amdgcn_sched_barrier(0);
    if (st) { stage_half(p, 0, 0, kt + 2); stage_half(p, 0, 1, kt + 2); }  // restage A(p)
    if (kt == NKT - 2) asm volatile("s_waitcnt vmcnt(0)" ::: "memory");
    else               asm volatile("s_waitcnt vmcnt(8)" ::: "memory");
    __builtin_amdgcn_s_barrier();   // B3: kt+1 buffers ready
    __builtin_amdgcn_sched_barrier(0);
  }

  #pragma unroll
  for (int m = 0; m < 8; ++m) {
    int row = row0 + wr*128 + m*16 + lk*4;
    #pragma unroll
    for (int n = 0; n < 4; ++n) {
      int col = col0 + wc*64 + n*16 + lr;
      #pragma unroll
      for (int j = 0; j < 4; ++j) {
        if (OBF) ((unsigned short*)Cv)[(size_t)(row + j) * N + col] = f2bf(acc[m][n][j]);
        else     ((float*)Cv)[(size_t)(row + j) * N + col] = acc[m][n][j];
      }
    }
  }
}

// ---------------- 256x128 bf16 MFMA GEMM — same relaxed schedule --------------------------
template<bool OBF>
__global__ __launch_bounds__(512, 2) void gemm256x128(const unsigned short* __restrict__ A,
                                                      const unsigned short* __restrict__ Bt,
                                                      void* __restrict__ Cv,
                                                      int M, int N, int K) {
  __shared__ char ldsb[98304];
  const int t    = threadIdx.x;
  const int lane = t & 63;
  const int wid  = t >> 6;
  const int wr   = wid >> 1;        // 0..3
  const int wc   = wid & 1;         // 0..1
  const int lr   = lane & 15;
  const int lk   = lane >> 4;       // 0..3
  int flat = blockIdx.y * gridDim.x + blockIdx.x;
  if (gridDim.x * gridDim.y == 256) flat = (flat & 7) * 32 + (flat >> 3);  // XCD-chunked
  const int row0 = (flat / gridDim.x) * 256;
  const int col0 = (flat % gridDim.x) * 128;
  const int NKT  = K >> 6;
  const size_t K2 = (size_t)K * 2;

  const int r_s  = t >> 2;
  const int kx_s = ((t & 3) * 16) ^ (((t >> 5) & 1) << 5);

  const int ha  = wr >> 1;
  const int ral = (wr & 1) * 64;
  const int rbl = wc * 64;

  f32x4 acc[4][4];
  #pragma unroll
  for (int m = 0; m < 4; ++m)
    #pragma unroll
    for (int n = 0; n < 4; ++n) acc[m][n] = (f32x4){0.f, 0.f, 0.f, 0.f};

  auto stage_slot = [&](int p, int slot, int kt) {
    const char* src = (slot == 2) ? (const char*)Bt : (const char*)A;
    const int R0 = (slot == 2) ? col0 : (row0 + slot * 128);
    const char* g = src + (size_t)(R0 + r_s) * K2 + (size_t)kt * 128 + kx_s;
    char* l = ldsb + p * 49152 + slot * 16384 + t * 16;
    gload16(g, l);
    gload16(g + 64, l + 8192);
  };
  auto lda = [&](int p, int mf, int ks) -> bf16x8 {
    int r = ral + mf * 16 + lr;
    int a = p * 49152 + ha * 16384 + ks * 8192 + r * 64 + lk * 16;
    a ^= ((r >> 3) & 1) << 5;
    return *(const bf16x8*)(ldsb + a);
  };
  auto ldb = [&](int p, int nf, int ks) -> bf16x8 {
    int r = rbl + nf * 16 + lr;
    int a = p * 49152 + 32768 + ks * 8192 + r * 64 + lk * 16;
    a ^= ((r >> 3) & 1) << 5;
    return *(const bf16x8*)(ldsb + a);
  };

  stage_slot(0, 2, 0); stage_slot(0, 0, 0); stage_slot(0, 1, 0);
  if (1 < NKT) { stage_slot(1, 2, 1); stage_slot(1, 0, 1); stage_slot(1, 1, 1); }
  asm volatile("s_waitcnt vmcnt(6)" ::: "memory");
  __builtin_amdgcn_s_barrier();
  __builtin_amdgcn_sched_barrier(0);

  bf16x8 fa[2][2], fb[2][2], fb2[2][2];

  for (int kt = 0; kt < NKT; ++kt) {
    const int p = kt & 1;
    const bool st = (kt + 2 < NKT);
    #pragma unroll
    for (int m = 0; m < 2; ++m) { fa[m][0] = lda(p, m, 0); fa[m][1] = lda(p, m, 1); }
    #pragma unroll
    for (int n = 0; n < 2; ++n) { fb[n][0] = ldb(p, n, 0); fb[n][1] = ldb(p, n, 1); }
    #pragma unroll
    for (int n = 0; n < 2; ++n) { fb2[n][0] = ldb(p, n + 2, 0); fb2[n][1] = ldb(p, n + 2, 1); }
    __builtin_amdgcn_s_setprio(1);
    #pragma unroll
    for (int m = 0; m < 2; ++m)
      #pragma unroll
      for (int n = 0; n < 2; ++n) {
        acc[m][n] = __builtin_amdgcn_mfma_f32_16x16x32_bf16(fa[m][0], fb[n][0], acc[m][n], 0, 0, 0);
        acc[m][n] = __builtin_amdgcn_mfma_f32_16x16x32_bf16(fa[m][1], fb[n][1], acc[m][n], 0, 0, 0);
      }
    #pragma unroll
    for (int m = 0; m < 2; ++m)
      #pragma unroll
      for (int n = 0; n < 2; ++n) {
        acc[m][n+2] = __builtin_amdgcn_mfma_f32_16x16x32_bf16(fa[m][0], fb2[n][0], acc[m][n+2], 0, 0, 0);
        acc[m][n+2] = __builtin_amdgcn_mfma_f32_16x16x32_bf16(fa[m][1], fb2[n][1], acc[m][n+2], 0, 0, 0);
      }
    __builtin_amdgcn_s_setprio(0);
    __builtin_amdgcn_sched_barrier(0);
    __builtin_amdgcn_s_barrier();   // B1
    __builtin_amdgcn_sched_barrier(0);
    if (st) stage_slot(p, 2, kt + 2);
    #pragma unroll
    for (int m = 0; m < 2; ++m) { fa[m][0] = lda(p, m + 2, 0); fa[m][1] = lda(p, m + 2, 1); }
    __builtin_amdgcn_s_setprio(1);
    #pragma unroll
    for (int m = 0; m < 2; ++m)
      #pragma unroll
      for (int n = 0; n < 2; ++n) {
        acc[m+2][n] = __builtin_amdgcn_mfma_f32_16x16x32_bf16(fa[m][0], fb[n][0], acc[m+2][n], 0, 0, 0);
        acc[m+2][n] = __builtin_amdgcn_mfma_f32_16x16x32_bf16(fa[m][1], fb[n][1], acc[m+2][n], 0, 0, 0);
      }
    #pragma unroll
    for (int m = 0; m < 2; ++m)
      #pragma unroll
      for (int n = 0; n < 2; ++n) {
        acc[m+2][n+2] = __builtin_amdgcn_mfma_f32_16x16x32_bf16(fa[m][0], fb2[n][0], acc[m+2][n+2], 0, 0, 0);
        acc[m+2][n+2] = __builtin_amdgcn_mfma_f32_16x16x32_bf16(fa[m][1], fb2[n][1], acc[m+2][n+2], 0, 0, 0);
      }
    __builtin_amdgcn_s_setprio(0);
    __builtin_amdgcn_sched_barrier(0);
    __builtin_amdgcn_s_barrier();   // B2
    __builtin_amdgcn_sched_barrier(0);
    if (st) { stage_slot(p, 0, kt + 2); stage_slot(p, 1, kt + 2); }
    if (kt == NKT - 2) asm volatile("s_waitcnt vmcnt(0)" ::: "memory");
    else               asm volatile("s_waitcnt vmcnt(6)" ::: "memory");
    __builtin_amdgcn_s_barrier();   // B3
    __builtin_amdgcn_sched_barrier(0);
  }

  #pragma unroll
  for (int m = 0; m < 4; ++m) {
    int row = row0 + wr*64 + m*16 + lk*4;
    #pragma unroll
    for (int n = 0; n < 4; ++n) {
      int col = col0 + wc*64 + n*16 + lr;
      #pragma unroll
      for (int j = 0; j < 4; ++j) {
        if (OBF) ((unsigned short*)Cv)[(size_t)(row + j) * N + col] = f2bf(acc[m][n][j]);
        else     ((float*)Cv)[(size_t)(row + j) * N + col] = acc[m][n][j];
      }
    }
  }
}

// ---------------- GLA phase A (MFMA): per-segment local state S^T in registers ------------
__global__ __launch_bounds__(256) void gla_phase_a(const unsigned short* __restrict__ qkb,
                                                   const unsigned short* __restrict__ vg,
                                                   const float* __restrict__ gk,
                                                   float* __restrict__ Sseg,
                                                   float* __restrict__ Dseg) {
  const int seg = blockIdx.x & 15;
  const int h   = (blockIdx.x >> 4) & 15;
  const int b   = blockIdx.x >> 8;
  const int t    = threadIdx.x;
  const int lane = t & 63;
  const int wid  = t >> 6;
  const int q    = lane >> 4;
  const int lr   = lane & 15;
  __shared__ float gc[16][68];
  __shared__ float dec_[64];
  __shared__ unsigned short kdT[64][40];   // [d][c], c>=16 zero
  __shared__ unsigned short vvT[128][40];  // [e][c], c>=16 zero

  for (int i = t; i < 1024; i += 256) kdT[i >> 4][16 + (i & 15)] = 0;
  for (int i = t; i < 2048; i += 256) vvT[i >> 4][16 + (i & 15)] = 0;

  f32x4 s_reg[2][4];
  #pragma unroll
  for (int et = 0; et < 2; ++et)
    #pragma unroll
    for (int dt = 0; dt < 4; ++dt) s_reg[et][dt] = (f32x4){0.f,0.f,0.f,0.f};
  float gt = 0.f;

  for (int c8 = 0; c8 < NCHUNK/NSEG; ++c8) {
    const int ch = seg * (NCHUNK/NSEG) + c8;
    __syncthreads();
    {
      float acc = 0.f;
      #pragma unroll
      for (int c = 0; c < CC; ++c) {
        acc += gk[((size_t)(b*T_ + ch*CC + c)) * 1024 + h*DK_ + lane];
        gc[c][lane] = acc;
      }
      gt += acc;
      dec_[lane] = expf(acc);
    }
    __syncthreads();
    {
      int c = t >> 4, d0 = (t & 15) * 4;
      ushort4 k4u = *reinterpret_cast<const ushort4*>(
          &qkb[((size_t)(b*T_ + ch*CC + c)) * 2048 + 1024 + h*DK_ + d0]);
      float ka[4] = {bf2f(k4u.x), bf2f(k4u.y), bf2f(k4u.z), bf2f(k4u.w)};
      #pragma unroll
      for (int j = 0; j < 4; ++j)
        kdT[d0 + j][c] = f2bf(ka[j] * expf(gc[CC-1][d0 + j] - gc[c][d0 + j]));
    }
    {
      int c = t & 15, e0 = (t >> 4) * 8;
      const ushort4* vp = reinterpret_cast<const ushort4*>(
          &vg[((size_t)(b*T_ + ch*CC + c)) * 4096 + h*DV_ + e0]);
      ushort4 a = vp[0], bb = vp[1];
      vvT[e0+0][c] = a.x;  vvT[e0+1][c] = a.y;  vvT[e0+2][c] = a.z;  vvT[e0+3][c] = a.w;
      vvT[e0+4][c] = bb.x; vvT[e0+5][c] = bb.y; vvT[e0+6][c] = bb.z; vvT[e0+7][c] = bb.w;
    }
    __syncthreads();
    bf16x8 vf[2], kf[4];
    #pragma unroll
    for (int et = 0; et < 2; ++et)
      vf[et] = *(const bf16x8*)&vvT[wid*32 + et*16 + lr][q*8];
    #pragma unroll
    for (int dt = 0; dt < 4; ++dt)
      kf[dt] = *(const bf16x8*)&kdT[dt*16 + lr][q*8];
    #pragma unroll
    for (int et = 0; et < 2; ++et)
      #pragma unroll
      for (int dt = 0; dt < 4; ++dt) {
        f32x4 dl = __builtin_amdgcn_mfma_f32_16x16x32_bf16(vf[et], kf[dt],
                     (f32x4){0.f,0.f,0.f,0.f}, 0, 0, 0);
        float dv = dec_[dt*16 + lr];
        #pragma unroll
        for (int j = 0; j < 4; ++j)
          s_reg[et][dt][j] = fmaf(s_reg[et][dt][j], dv, dl[j]);
      }
  }
  const size_t base = ((size_t)((b*H_ + h)*NSEG + seg)) * (DK_*DV_);
  #pragma unroll
  for (int et = 0; et < 2; ++et)
    #pragma unroll
    for (int dt = 0; dt < 4; ++dt)
      #pragma unroll
      for (int j = 0; j < 4; ++j)
        Sseg[base + (size_t)(wid*32 + et*16 + q*4 + j) * 64 + dt*16 + lr] = s_reg[et][dt][j];
  if (t < 64)
    Dseg[(size_t)((b*H_ + h)*NSEG + seg) * DK_ + t] = expf(gt);
}

// ---------------- GLA phase B: sequential combine over segments (Sseg is [e][d]) ----------
__global__ __launch_bounds__(256) void gla_combine(float* __restrict__ Sseg,
                                                   const float* __restrict__ Dseg) {
  const int bh = blockIdx.x;
  const int t = threadIdx.x;
  __shared__ float Dl[64];
  float4 S_run[8];
  #pragma unroll
  for (int j = 0; j < 8; ++j) S_run[j] = (float4){0.f,0.f,0.f,0.f};
  const int d0 = (t * 4) & 63;
  for (int seg = 0; seg < NSEG; ++seg) {
    const size_t base = ((size_t)bh*NSEG + seg) * (DK_*DV_);
    if (t < 64) Dl[t] = Dseg[((size_t)bh*NSEG + seg) * DK_ + t];
    __syncthreads();
    #pragma unroll
    for (int j = 0; j < 8; ++j) {
      int idx = j*1024 + t*4;
      float4 sl = *reinterpret_cast<float4*>(&Sseg[base + idx]);
      *reinterpret_cast<float4*>(&Sseg[base + idx]) = S_run[j];
      S_run[j].x = fmaf(Dl[d0+0], S_run[j].x, sl.x);
      S_run[j].y = fmaf(Dl[d0+1], S_run[j].y, sl.y);
      S_run[j].z = fmaf(Dl[d0+2], S_run[j].z, sl.z);
      S_run[j].w = fmaf(Dl[d0+3], S_run[j].w, sl.w);
    }
    __syncthreads();
  }
}

// ---------------- GLA phase C (MFMA): outputs + state march + fused RMSNorm/SiLU epilogue -
__global__ __launch_bounds__(256) void gla_phase_c(const unsigned short* __restrict__ qkb,
                                                   const unsigned short* __restrict__ vg,
                                                   const float* __restrict__ gk,
                                                   const float* __restrict__ Sseg,
                                                   const float* __restrict__ norm_w,
                                                   unsigned short* __restrict__ yb) {
  const int seg = blockIdx.x & 15;
  const int h   = (blockIdx.x >> 4) & 15;
  const int b   = blockIdx.x >> 8;
  const int t    = threadIdx.x;
  const int lane = t & 63;
  const int wid  = t >> 6;
  const int q    = lane >> 4;
  const int lr   = lane & 15;
  __shared__ float gc[16][68];
  __shared__ float dec_[64];
  __shared__ unsigned short qe[16][72];    // [c][d]
  __shared__ unsigned short ke[16][72];    // [m][d]
  __shared__ unsigned short kdT[64][40];   // [d][c], c>=16 zero
  __shared__ unsigned short vvT[128][40];  // [e][c], c>=16 zero
  __shared__ unsigned short Am[16][40];    // [c][m], m>=16 zero
  __shared__ unsigned short Sb[128][72];   // [e][d] bf16 shadow of S^T
  __shared__ float ss_lds[4][16];
  __shared__ float nw[128];

  for (int i = t; i < 1024; i += 256) kdT[i >> 4][16 + (i & 15)] = 0;
  for (int i = t; i < 2048; i += 256) vvT[i >> 4][16 + (i & 15)] = 0;
  if (t < 256) { int c = t >> 4, m = t & 15; Am[c][16 + m] = 0; }
  if (t < 128) nw[t] = norm_w[t];

  f32x4 s_reg[2][4];
  const size_t sbase = ((size_t)((b*H_ + h)*NSEG + seg)) * (DK_*DV_);
  #pragma unroll
  for (int et = 0; et < 2; ++et)
    #pragma unroll
    for (int dt = 0; dt < 4; ++dt)
      #pragma unroll
      for (int j = 0; j < 4; ++j) {
        int e = wid*32 + et*16 + q*4 + j, d = dt*16 + lr;
        float v = Sseg[sbase + (size_t)e * 64 + d];
        s_reg[et][dt][j] = v;
        Sb[e][d] = f2bf(v);
      }

  for (int c8 = 0; c8 < NCHUNK/NSEG; ++c8) {
    const int ch = seg * (NCHUNK/NSEG) + c8;
    __syncthreads();
    {
      float acc = 0.f;
      #pragma unroll
      for (int c = 0; c < CC; ++c) {
        acc += gk[((size_t)(b*T_ + ch*CC + c)) * 1024 + h*DK_ + lane];
        gc[c][lane] = acc;
      }
      dec_[lane] = expf(acc);
    }
    __syncthreads();
    {
      int c = t >> 4, d0 = (t & 15) * 4;
      const size_t gbq = ((size_t)(b*T_ + ch*CC + c)) * 2048 + h*DK_ + d0;
      ushort4 q4u = *reinterpret_cast<const ushort4*>(&qkb[gbq]);
      ushort4 k4u = *reinterpret_cast<const ushort4*>(&qkb[gbq + 1024]);
      float qa[4] = {bf2f(q4u.x), bf2f(q4u.y), bf2f(q4u.z), bf2f(q4u.w)};
      float ka[4] = {bf2f(k4u.x), bf2f(k4u.y), bf2f(k4u.z), bf2f(k4u.w)};
      ushort4 qw, kw;
      unsigned short* qwp = (unsigned short*)&qw;
      unsigned short* kwp = (unsigned short*)&kw;
      #pragma unroll
      for (int j = 0; j < 4; ++j) {
        float gcv = gc[c][d0 + j];
        float gl  = gc[CC-1][d0 + j];
        qwp[j] = f2bf(qa[j] * expf(gcv) * SCALE_);
        kwp[j] = f2bf(ka[j] * expf(-gcv));
        kdT[d0 + j][c] = f2bf(ka[j] * expf(gl - gcv));
      }
      *reinterpret_cast<ushort4*>(&qe[c][d0]) = qw;
      *reinterpret_cast<ushort4*>(&ke[c][d0]) = kw;
    }
    {
      int c = t & 15, e0 = (t >> 4) * 8;
      const ushort4* vp = reinterpret_cast<const ushort4*>(
          &vg[((size_t)(b*T_ + ch*CC + c)) * 4096 + h*DV_ + e0]);
      ushort4 a = vp[0], bb = vp[1];
      vvT[e0+0][c] = a.x;  vvT[e0+1][c] = a.y;  vvT[e0+2][c] = a.z;  vvT[e0+3][c] = a.w;
      vvT[e0+4][c] = bb.x; vvT[e0+5][c] = bb.y; vvT[e0+6][c] = bb.z; vvT[e0+7][c] = bb.w;
    }
    __syncthreads();
    bf16x8 qA0 = *(const bf16x8*)&qe[lr][q*8];
    bf16x8 qA1 = *(const bf16x8*)&qe[lr][32 + q*8];
    {
      bf16x8 kB0 = *(const bf16x8*)&ke[lr][q*8];
      bf16x8 kB1 = *(const bf16x8*)&ke[lr][32 + q*8];
      f32x4 accA = __builtin_amdgcn_mfma_f32_16x16x32_bf16(qA0, kB0,
                     (f32x4){0.f,0.f,0.f,0.f}, 0, 0, 0);
      accA = __builtin_amdgcn_mfma_f32_16x16x32_bf16(qA1, kB1, accA, 0, 0, 0);
      #pragma unroll
      for (int j = 0; j < 4; ++j) {
        int c = q*4 + j;
        Am[c][lr] = (lr <= c) ? f2bf(accA[j]) : (unsigned short)0;
      }
    }
    bf16x8 vf[2], kf[4];
    #pragma unroll
    for (int et = 0; et < 2; ++et)
      vf[et] = *(const bf16x8*)&vvT[wid*32 + et*16 + lr][q*8];
    #pragma unroll
    for (int dt = 0; dt < 4; ++dt)
      kf[dt] = *(const bf16x8*)&kdT[dt*16 + lr][q*8];
    #pragma unroll
    for (int et = 0; et < 2; ++et)
      #pragma unroll
      for (int dt = 0; dt < 4; ++dt) {
        f32x4 dl = __builtin_amdgcn_mfma_f32_16x16x32_bf16(vf[et], kf[dt],
                     (f32x4){0.f,0.f,0.f,0.f}, 0, 0, 0);
        float dv = dec_[dt*16 + lr];
        #pragma unroll
        for (int j = 0; j < 4; ++j)
          s_reg[et][dt][j] = fmaf(s_reg[et][dt][j], dv, dl[j]);
      }
    __syncthreads();
    {
      bf16x8 amA = *(const bf16x8*)&Am[lr][q*8];
      f32x4 accO[2];
      #pragma unroll
      for (int et = 0; et < 2; ++et) {
        int e0 = wid*32 + et*16;
        bf16x8 sB0 = *(const bf16x8*)&Sb[e0 + lr][q*8];
        bf16x8 sB1 = *(const bf16x8*)&Sb[e0 + lr][32 + q*8];
        accO[et] = __builtin_amdgcn_mfma_f32_16x16x32_bf16(qA0, sB0,
                     (f32x4){0.f,0.f,0.f,0.f}, 0, 0, 0);
        accO[et] = __builtin_amdgcn_mfma_f32_16x16x32_bf16(qA1, sB1, accO[et], 0, 0, 0);
        accO[et] = __builtin_amdgcn_mfma_f32_16x16x32_bf16(amA, vf[et], accO[et], 0, 0, 0);
      }
      #pragma unroll
      for (int j = 0; j < 4; ++j) {
        float pj = accO[0][j]*accO[0][j] + accO[1][j]*accO[1][j];
        pj += __shfl_xor(pj, 1, 64);
        pj += __shfl_xor(pj, 2, 64);
        pj += __shfl_xor(pj, 4, 64);
        pj += __shfl_xor(pj, 8, 64);
        if (lr == 0) ss_lds[wid][q*4 + j] = pj;
      }
      __syncthreads();
      #pragma unroll
      for (int j = 0; j < 4; ++j) {
        int r = q*4 + j;
        float tot = ss_lds[0][r] + ss_lds[1][r] + ss_lds[2][r] + ss_lds[3][r];
        float inv = rsqrtf(tot * (1.f/128.f) + 1e-5f);
        const size_t rowg = (size_t)(b*T_ + ch*CC + r);
        #pragma unroll
        for (int et = 0; et < 2; ++et) {
          int e = wid*32 + et*16 + lr;
          float gv = bf2f(vg[rowg * 4096 + 2048 + h*DV_ + e]);
          float si = gv / (1.f + expf(-gv));
          yb[rowg * 2048 + h*DV_ + e] = f2bf(accO[et][j] * inv * nw[e] * si);
        }
      }
    }
    __syncthreads();
    #pragma unroll
    for (int et = 0; et < 2; ++et)
      #pragma unroll
      for (int dt = 0; dt < 4; ++dt)
        #pragma unroll
        for (int j = 0; j < 4; ++j)
          Sb[wid*32 + et*16 + q*4 + j][dt*16 + lr] = f2bf(s_reg[et][dt][j]);
  }
}

// ------------------------------------------------------------------------------------------
extern "C" void kernel_launch(void* const* d_in, const int* in_sizes, int n_in,
                              void* d_out, int out_size, void* d_ws, size_t ws_size,
                              hipStream_t stream) {
  const float* x      = (const float*)d_in[0];
  const float* Wq     = (const float*)d_in[1];
  const float* Wk     = (const float*)d_in[2];
  const float* Wv     = (const float*)d_in[3];
  const float* Wg     = (const float*)d_in[4];
  const float* Wgk1   = (const float*)d_in[5];
  const float* Wgk2   = (const float*)d_in[6];
  const float* bgk2   = (const float*)d_in[7];
  const float* Wo     = (const float*)d_in[8];
  const float* norm_w = (const float*)d_in[9];
  float* out = (float*)d_out;
  float* ws  = (float*)d_ws;

  // ws layout (float-element offsets)
  unsigned short* qkb  = (unsigned short*)ws;              // bf16 [M][2048] q|k
  float*          gkb  = ws + 8388608;                     // f32 [M][1024]
  unsigned short* vg   = (unsigned short*)(ws + 12582912); // bf16 [M][4096] v|g
  float*          wbuf = ws + 20971520;                    // transient weights / yb region
  float*          Sseg = ws + 29360128;                    // f32 [B*H*NSEG][128e][64d]
  float*          Dseg = ws + 33554432;                    // 32768 f32
  unsigned short* WoT  = (unsigned short*)(ws + 33652736); // bf16 [2048][2048] (dedicated)

  // lifetime-disjoint aliases (stream order makes these safe)
  unsigned short* WqkT = (unsigned short*)wbuf;            // dead after qk GEMM
  unsigned short* WvgT = (unsigned short*)(wbuf + 2097152);// dead after vg GEMM
  unsigned short* xb   = (unsigned short*)(wbuf + 6291456);// bf16 [M][2048]; dead after GEMMs
  unsigned short* yb   = (unsigned short*)wbuf;            // phase_c output (WqkT/WvgT dead)

  dim3 blk(256);
  // lr gate (first, hidden under streaming) + x convert + LDS-free weight transposes
  prep_kernel<<<dim3(4096), blk, 0, stream>>>(x, xb, Wq, Wk, Wv, Wg, Wo, WqkT, WvgT, WoT,
                                              Wgk1, Wgk2, bgk2, gkb);
  gemm256x128<true ><<<dim3(2048/128, 4096/256), dim3(512), 0, stream>>>(xb, WqkT, qkb, M_, 2048, HID_);
  gemm256<true     ><<<dim3(4096/256, 4096/256), dim3(512), 0, stream>>>(xb, WvgT, vg, M_, 4096, HID_);
  gla_phase_a<<<B_*H_*NSEG, blk, 0, stream>>>(qkb, vg, gkb, Sseg, Dseg);
  gla_combine<<<B_*H_, blk, 0, stream>>>(Sseg, Dseg);
  gla_phase_c<<<B_*H_*NSEG, blk, 0, stream>>>(qkb, vg, gkb, Sseg, norm_w, yb);
  gemm256x128<false><<<dim3(2048/128, 4096/256), dim3(512), 0, stream>>>(yb, WoT, out, M_, HID_, HID_);
}

// Round 18
// 279.512 us; speedup vs baseline: 1.0659x; 1.0659x over previous
//
#include <hip/hip_runtime.h>
#include <hip/hip_bf16.h>
#include <math.h>

// Problem constants
#define B_    2
#define T_    2048
#define HID_  2048
#define H_    16
#define DK_   64
#define DV_   128
#define CC    16
#define NCHUNK (T_/CC)     // 128
#define NSEG  16           // segments per (b,h); 8 chunks each
#define M_    (B_*T_)      // 4096
#define SCALE_ 0.125f      // DK^-0.5

typedef __attribute__((ext_vector_type(8))) __bf16 bf16x8;
typedef __attribute__((ext_vector_type(8))) unsigned short u16x8;
typedef __attribute__((ext_vector_type(4))) float f32x4;

__device__ __forceinline__ unsigned short f2bf(float f) {
  unsigned int u = __float_as_uint(f);
  u += 0x7fff + ((u >> 16) & 1);   // RNE
  return (unsigned short)(u >> 16);
}
__device__ __forceinline__ float bf2f(unsigned short u) {
  return __uint_as_float(((unsigned int)u) << 16);
}

typedef const __attribute__((address_space(1))) void* as1cv;
typedef __attribute__((address_space(3))) void* as3v;
__device__ __forceinline__ void gload16(const void* g, void* l) {
  __builtin_amdgcn_global_load_lds((as1cv)g, (as3v)l, 16, 0, 0);
}

// ------ fused prep: low-rank gate FIRST (hidden under streaming), then convert/transposes -
// [0,1024): lr gate (4 rows/block); [1024,3072): x convert; [3072,7168): transpose tiles
__global__ __launch_bounds__(256) void prep_kernel(const float* __restrict__ x,
                                                   unsigned short* __restrict__ xb,
                                                   const float* __restrict__ Wq,
                                                   const float* __restrict__ Wk,
                                                   const float* __restrict__ Wv,
                                                   const float* __restrict__ Wg,
                                                   const float* __restrict__ Wo,
                                                   unsigned short* __restrict__ WqkT,
                                                   unsigned short* __restrict__ WvgT,
                                                   unsigned short* __restrict__ WoT,
                                                   const float* __restrict__ w1,
                                                   const float* __restrict__ w2,
                                                   const float* __restrict__ bias,
                                                   float* __restrict__ gkout) {
  const int t = threadIdx.x;
  int id = blockIdx.x;
  if (id < 1024) {
    // low-rank gate: gk = log_sigmoid(x@W1@W2 + b)/16, 4 rows per block
    __shared__ float part[4][4][17];
    __shared__ float t1s[4][16];
    const int row0 = id * 4;
    const int r    = t >> 6;
    const int lane = t & 63;
    const int j    = lane & 15;
    const int p    = lane >> 4;
    const float* xr = x + (size_t)(row0 + r) * HID_;
    float acc = 0.f;
    const int k0 = p * 512;
    for (int kk = k0; kk < k0 + 512; kk += 4) {
      float4 xv = *reinterpret_cast<const float4*>(&xr[kk]);
      acc = fmaf(xv.x, w1[(kk+0)*16 + j], acc);
      acc = fmaf(xv.y, w1[(kk+1)*16 + j], acc);
      acc = fmaf(xv.z, w1[(kk+2)*16 + j], acc);
      acc = fmaf(xv.w, w1[(kk+3)*16 + j], acc);
    }
    part[r][p][j] = acc;
    __syncthreads();
    if (t < 64) {
      int rr = t >> 4, jj = t & 15;
      t1s[rr][jj] = part[rr][0][jj] + part[rr][1][jj] + part[rr][2][jj] + part[rr][3][jj];
    }
    __syncthreads();
    #pragma unroll
    for (int i = 0; i < 4; ++i) {
      int n = t + i * 256;
      float b0 = bias[n];
      float a0 = b0, a1 = b0, a2 = b0, a3 = b0;
      #pragma unroll
      for (int jj = 0; jj < 16; ++jj) {
        float wv = w2[jj * 1024 + n];
        a0 = fmaf(t1s[0][jj], wv, a0);
        a1 = fmaf(t1s[1][jj], wv, a1);
        a2 = fmaf(t1s[2][jj], wv, a2);
        a3 = fmaf(t1s[3][jj], wv, a3);
      }
      gkout[(size_t)(row0+0)*1024 + n] = (fminf(a0,0.f) - log1pf(expf(-fabsf(a0)))) * (1.f/16.f);
      gkout[(size_t)(row0+1)*1024 + n] = (fminf(a1,0.f) - log1pf(expf(-fabsf(a1)))) * (1.f/16.f);
      gkout[(size_t)(row0+2)*1024 + n] = (fminf(a2,0.f) - log1pf(expf(-fabsf(a2)))) * (1.f/16.f);
      gkout[(size_t)(row0+3)*1024 + n] = (fminf(a3,0.f) - log1pf(expf(-fabsf(a3)))) * (1.f/16.f);
    }
    return;
  }
  id -= 1024;
  if (id < 2048) {
    const float4* x4 = reinterpret_cast<const float4*>(x);
    ushort4* o4 = reinterpret_cast<ushort4*>(xb);
    const int base = id * 1024 + t;
    float4 f0 = x4[base];
    float4 f1 = x4[base + 256];
    float4 f2 = x4[base + 512];
    float4 f3 = x4[base + 768];
    ushort4 u0 = {f2bf(f0.x), f2bf(f0.y), f2bf(f0.z), f2bf(f0.w)};
    ushort4 u1 = {f2bf(f1.x), f2bf(f1.y), f2bf(f1.z), f2bf(f1.w)};
    ushort4 u2 = {f2bf(f2.x), f2bf(f2.y), f2bf(f2.z), f2bf(f2.w)};
    ushort4 u3 = {f2bf(f3.x), f2bf(f3.y), f2bf(f3.z), f2bf(f3.w)};
    o4[base] = u0; o4[base + 256] = u1; o4[base + 512] = u2; o4[base + 768] = u3;
    return;
  }
  id -= 2048;
  const float* in; unsigned short* out; int N;
  if (id < 512)        { in = Wq; out = WqkT;                         N = 1024; }
  else if (id < 1024)  { in = Wk; out = WqkT + (size_t)1024*2048;     N = 1024; id -= 512; }
  else if (id < 2048)  { in = Wv; out = WvgT;                         N = 2048; id -= 1024; }
  else if (id < 3072)  { in = Wg; out = WvgT + (size_t)2048*2048;     N = 2048; id -= 2048; }
  else                 { in = Wo; out = WoT;                          N = 2048; id -= 3072; }
  const int nx = N / 64;
  const int n0 = (id % nx) * 64;
  const int k0 = (id / nx) * 64;
  __shared__ float tl[64][65];
  const int kr = t >> 4;
  const int nq = t & 15;
  #pragma unroll
  for (int it = 0; it < 4; ++it) {
    int kk = it*16 + kr;
    float4 v = *reinterpret_cast<const float4*>(&in[(size_t)(k0 + kk) * N + n0 + nq*4]);
    tl[kk][nq*4+0] = v.x; tl[kk][nq*4+1] = v.y;
    tl[kk][nq*4+2] = v.z; tl[kk][nq*4+3] = v.w;
  }
  __syncthreads();
  const int nr = t >> 3;
  const int kq = t & 7;
  #pragma unroll
  for (int it = 0; it < 2; ++it) {
    int nn = it*32 + nr;
    u16x8 u;
    #pragma unroll
    for (int r = 0; r < 8; ++r) u[r] = f2bf(tl[kq*8 + r][nn]);
    *reinterpret_cast<u16x8*>(&out[(size_t)(n0 + nn) * 2048 + k0 + kq*8]) = u;
  }
}

// ---------------- 256x256 bf16 MFMA GEMM — compiler-scheduled, 3-barrier ledger -----------
template<bool OBF>
__global__ __launch_bounds__(512, 2) void gemm256(const unsigned short* __restrict__ A,
                                                  const unsigned short* __restrict__ Bt,
                                                  void* __restrict__ Cv,
                                                  int M, int N, int K) {
  __shared__ char ldsb[131072];
  const int t    = threadIdx.x;
  const int lane = t & 63;
  const int wid  = t >> 6;
  const int wr   = wid >> 2;        // 0..1
  const int wc   = wid & 3;         // 0..3
  const int lr   = lane & 15;
  const int lk   = lane >> 4;       // 0..3
  int flat = blockIdx.y * gridDim.x + blockIdx.x;
  if (gridDim.x * gridDim.y == 256) flat = (flat & 7) * 32 + (flat >> 3);  // XCD-chunked
  const int row0 = (flat / gridDim.x) * 256;
  const int col0 = (flat % gridDim.x) * 256;
  const int NKT  = K >> 6;
  const size_t K2 = (size_t)K * 2;

  const int r_s  = t >> 2;
  const int kx_s = ((t & 3) * 16) ^ (((t >> 5) & 1) << 5);

  const int ha = wr;
  const int hb = wc >> 1;
  const int rbl = (wc & 1) * 64;

  f32x4 acc[8][4];
  #pragma unroll
  for (int m = 0; m < 8; ++m)
    #pragma unroll
    for (int n = 0; n < 4; ++n) acc[m][n] = (f32x4){0.f, 0.f, 0.f, 0.f};

  auto stage_half = [&](int p, int o, int h, int kt) {
    const char* src = o ? (const char*)Bt : (const char*)A;
    const int R0 = (o ? col0 : row0) + h * 128;
    const char* g = src + (size_t)(R0 + r_s) * K2 + (size_t)kt * 128 + kx_s;
    char* l = ldsb + ((((p << 1) | o) << 1 | h) << 14) + t * 16;
    gload16(g, l);
    gload16(g + 64, l + 8192);
  };
  auto lda = [&](int p, int mf, int ks) -> bf16x8 {
    int r = mf * 16 + lr;
    int a = ((((p << 1) | 0) << 1 | ha) << 14) + ks * 8192 + r * 64 + lk * 16;
    a ^= ((r >> 3) & 1) << 5;
    return *(const bf16x8*)(ldsb + a);
  };
  auto ldb = [&](int p, int nf, int ks) -> bf16x8 {
    int r = rbl + nf * 16 + lr;
    int a = ((((p << 1) | 1) << 1 | hb) << 14) + ks * 8192 + r * 64 + lk * 16;
    a ^= ((r >> 3) & 1) << 5;
    return *(const bf16x8*)(ldsb + a);
  };

  stage_half(0, 1, 0, 0); stage_half(0, 1, 1, 0);
  stage_half(0, 0, 0, 0); stage_half(0, 0, 1, 0);
  if (1 < NKT) {
    stage_half(1, 1, 0, 1); stage_half(1, 1, 1, 1);
    stage_half(1, 0, 0, 1); stage_half(1, 0, 1, 1);
  }
  asm volatile("s_waitcnt vmcnt(8)" ::: "memory");
  __builtin_amdgcn_s_barrier();
  __builtin_amdgcn_sched_barrier(0);

  bf16x8 fa[4][2], fb[2][2], fb2[2][2];

  for (int kt = 0; kt < NKT; ++kt) {
    const int p = kt & 1;
    const bool st = (kt + 2 < NKT);
    #pragma unroll
    for (int m = 0; m < 4; ++m) { fa[m][0] = lda(p, m, 0); fa[m][1] = lda(p, m, 1); }
    #pragma unroll
    for (int n = 0; n < 2; ++n) { fb[n][0] = ldb(p, n, 0); fb[n][1] = ldb(p, n, 1); }
    #pragma unroll
    for (int n = 0; n < 2; ++n) { fb2[n][0] = ldb(p, n + 2, 0); fb2[n][1] = ldb(p, n + 2, 1); }
    __builtin_amdgcn_s_setprio(1);
    #pragma unroll
    for (int m = 0; m < 4; ++m)
      #pragma unroll
      for (int n = 0; n < 2; ++n) {
        acc[m][n] = __builtin_amdgcn_mfma_f32_16x16x32_bf16(fa[m][0], fb[n][0], acc[m][n], 0, 0, 0);
        acc[m][n] = __builtin_amdgcn_mfma_f32_16x16x32_bf16(fa[m][1], fb[n][1], acc[m][n], 0, 0, 0);
      }
    #pragma unroll
    for (int m = 0; m < 4; ++m)
      #pragma unroll
      for (int n = 0; n < 2; ++n) {
        acc[m][n+2] = __builtin_amdgcn_mfma_f32_16x16x32_bf16(fa[m][0], fb2[n][0], acc[m][n+2], 0, 0, 0);
        acc[m][n+2] = __builtin_amdgcn_mfma_f32_16x16x32_bf16(fa[m][1], fb2[n][1], acc[m][n+2], 0, 0, 0);
      }
    __builtin_amdgcn_s_setprio(0);
    __builtin_amdgcn_sched_barrier(0);
    __builtin_amdgcn_s_barrier();   // B1: all waves done reading B(p) + fa0-3
    __builtin_amdgcn_sched_barrier(0);
    if (st) { stage_half(p, 1, 0, kt + 2); stage_half(p, 1, 1, kt + 2); }  // restage B(p)
    #pragma unroll
    for (int m = 0; m < 4; ++m) { fa[m][0] = lda(p, m + 4, 0); fa[m][1] = lda(p, m + 4, 1); }
    __builtin_amdgcn_s_setprio(1);
    #pragma unroll
    for (int m = 0; m < 4; ++m)
      #pragma unroll
      for (int n = 0; n < 2; ++n) {
        acc[m+4][n] = __builtin_amdgcn_mfma_f32_16x16x32_bf16(fa[m][0], fb[n][0], acc[m+4][n], 0, 0, 0);
        acc[m+4][n] = __builtin_amdgcn_mfma_f32_16x16x32_bf16(fa[m][1], fb[n][1], acc[m+4][n], 0, 0, 0);
      }
    #pragma unroll
    for (int m = 0; m < 4; ++m)
      #pragma unroll
      for (int n = 0; n < 2; ++n) {
        acc[m+4][n+2] = __builtin_amdgcn_mfma_f32_16x16x32_bf16(fa[m][0], fb2[n][0], acc[m+4][n+2], 0, 0, 0);
        acc[m+4][n+2] = __builtin_amdgcn_mfma_f32_16x16x32_bf16(fa[m][1], fb2[n][1], acc[m+4][n+2], 0, 0, 0);
      }
    __builtin_amdgcn_s_setprio(0);
    __builtin_amdgcn_sched_barrier(0);
    __builtin_amdgcn_s_barrier();   // B2: all waves done reading A(p)
    __builtin_amdgcn_sched_barrier(0);
    if (st) { stage_half(p, 0, 0, kt + 2); stage_half(p, 0, 1, kt + 2); }  // restage A(p)
    if (kt == NKT - 2) asm volatile("s_waitcnt vmcnt(0)" ::: "memory");
    else               asm volatile("s_waitcnt vmcnt(8)" ::: "memory");
    __builtin_amdgcn_s_barrier();   // B3: kt+1 buffers ready
    __builtin_amdgcn_sched_barrier(0);
  }

  #pragma unroll
  for (int m = 0; m < 8; ++m) {
    int row = row0 + wr*128 + m*16 + lk*4;
    #pragma unroll
    for (int n = 0; n < 4; ++n) {
      int col = col0 + wc*64 + n*16 + lr;
      #pragma unroll
      for (int j = 0; j < 4; ++j) {
        if (OBF) ((unsigned short*)Cv)[(size_t)(row + j) * N + col] = f2bf(acc[m][n][j]);
        else     ((float*)Cv)[(size_t)(row + j) * N + col] = acc[m][n][j];
      }
    }
  }
}

// ---------------- 256x128 bf16 MFMA GEMM — same relaxed schedule --------------------------
template<bool OBF>
__global__ __launch_bounds__(512, 2) void gemm256x128(const unsigned short* __restrict__ A,
                                                      const unsigned short* __restrict__ Bt,
                                                      void* __restrict__ Cv,
                                                      int M, int N, int K) {
  __shared__ char ldsb[98304];
  const int t    = threadIdx.x;
  const int lane = t & 63;
  const int wid  = t >> 6;
  const int wr   = wid >> 1;        // 0..3
  const int wc   = wid & 1;         // 0..1
  const int lr   = lane & 15;
  const int lk   = lane >> 4;       // 0..3
  int flat = blockIdx.y * gridDim.x + blockIdx.x;
  if (gridDim.x * gridDim.y == 256) flat = (flat & 7) * 32 + (flat >> 3);  // XCD-chunked
  const int row0 = (flat / gridDim.x) * 256;
  const int col0 = (flat % gridDim.x) * 128;
  const int NKT  = K >> 6;
  const size_t K2 = (size_t)K * 2;

  const int r_s  = t >> 2;
  const int kx_s = ((t & 3) * 16) ^ (((t >> 5) & 1) << 5);

  const int ha  = wr >> 1;
  const int ral = (wr & 1) * 64;
  const int rbl = wc * 64;

  f32x4 acc[4][4];
  #pragma unroll
  for (int m = 0; m < 4; ++m)
    #pragma unroll
    for (int n = 0; n < 4; ++n) acc[m][n] = (f32x4){0.f, 0.f, 0.f, 0.f};

  auto stage_slot = [&](int p, int slot, int kt) {
    const char* src = (slot == 2) ? (const char*)Bt : (const char*)A;
    const int R0 = (slot == 2) ? col0 : (row0 + slot * 128);
    const char* g = src + (size_t)(R0 + r_s) * K2 + (size_t)kt * 128 + kx_s;
    char* l = ldsb + p * 49152 + slot * 16384 + t * 16;
    gload16(g, l);
    gload16(g + 64, l + 8192);
  };
  auto lda = [&](int p, int mf, int ks) -> bf16x8 {
    int r = ral + mf * 16 + lr;
    int a = p * 49152 + ha * 16384 + ks * 8192 + r * 64 + lk * 16;
    a ^= ((r >> 3) & 1) << 5;
    return *(const bf16x8*)(ldsb + a);
  };
  auto ldb = [&](int p, int nf, int ks) -> bf16x8 {
    int r = rbl + nf * 16 + lr;
    int a = p * 49152 + 32768 + ks * 8192 + r * 64 + lk * 16;
    a ^= ((r >> 3) & 1) << 5;
    return *(const bf16x8*)(ldsb + a);
  };

  stage_slot(0, 2, 0); stage_slot(0, 0, 0); stage_slot(0, 1, 0);
  if (1 < NKT) { stage_slot(1, 2, 1); stage_slot(1, 0, 1); stage_slot(1, 1, 1); }
  asm volatile("s_waitcnt vmcnt(6)" ::: "memory");
  __builtin_amdgcn_s_barrier();
  __builtin_amdgcn_sched_barrier(0);

  bf16x8 fa[2][2], fb[2][2], fb2[2][2];

  for (int kt = 0; kt < NKT; ++kt) {
    const int p = kt & 1;
    const bool st = (kt + 2 < NKT);
    #pragma unroll
    for (int m = 0; m < 2; ++m) { fa[m][0] = lda(p, m, 0); fa[m][1] = lda(p, m, 1); }
    #pragma unroll
    for (int n = 0; n < 2; ++n) { fb[n][0] = ldb(p, n, 0); fb[n][1] = ldb(p, n, 1); }
    #pragma unroll
    for (int n = 0; n < 2; ++n) { fb2[n][0] = ldb(p, n + 2, 0); fb2[n][1] = ldb(p, n + 2, 1); }
    __builtin_amdgcn_s_setprio(1);
    #pragma unroll
    for (int m = 0; m < 2; ++m)
      #pragma unroll
      for (int n = 0; n < 2; ++n) {
        acc[m][n] = __builtin_amdgcn_mfma_f32_16x16x32_bf16(fa[m][0], fb[n][0], acc[m][n], 0, 0, 0);
        acc[m][n] = __builtin_amdgcn_mfma_f32_16x16x32_bf16(fa[m][1], fb[n][1], acc[m][n], 0, 0, 0);
      }
    #pragma unroll
    for (int m = 0; m < 2; ++m)
      #pragma unroll
      for (int n = 0; n < 2; ++n) {
        acc[m][n+2] = __builtin_amdgcn_mfma_f32_16x16x32_bf16(fa[m][0], fb2[n][0], acc[m][n+2], 0, 0, 0);
        acc[m][n+2] = __builtin_amdgcn_mfma_f32_16x16x32_bf16(fa[m][1], fb2[n][1], acc[m][n+2], 0, 0, 0);
      }
    __builtin_amdgcn_s_setprio(0);
    __builtin_amdgcn_sched_barrier(0);
    __builtin_amdgcn_s_barrier();   // B1
    __builtin_amdgcn_sched_barrier(0);
    if (st) stage_slot(p, 2, kt + 2);
    #pragma unroll
    for (int m = 0; m < 2; ++m) { fa[m][0] = lda(p, m + 2, 0); fa[m][1] = lda(p, m + 2, 1); }
    __builtin_amdgcn_s_setprio(1);
    #pragma unroll
    for (int m = 0; m < 2; ++m)
      #pragma unroll
      for (int n = 0; n < 2; ++n) {
        acc[m+2][n] = __builtin_amdgcn_mfma_f32_16x16x32_bf16(fa[m][0], fb[n][0], acc[m+2][n], 0, 0, 0);
        acc[m+2][n] = __builtin_amdgcn_mfma_f32_16x16x32_bf16(fa[m][1], fb[n][1], acc[m+2][n], 0, 0, 0);
      }
    #pragma unroll
    for (int m = 0; m < 2; ++m)
      #pragma unroll
      for (int n = 0; n < 2; ++n) {
        acc[m+2][n+2] = __builtin_amdgcn_mfma_f32_16x16x32_bf16(fa[m][0], fb2[n][0], acc[m+2][n+2], 0, 0, 0);
        acc[m+2][n+2] = __builtin_amdgcn_mfma_f32_16x16x32_bf16(fa[m][1], fb2[n][1], acc[m+2][n+2], 0, 0, 0);
      }
    __builtin_amdgcn_s_setprio(0);
    __builtin_amdgcn_sched_barrier(0);
    __builtin_amdgcn_s_barrier();   // B2
    __builtin_amdgcn_sched_barrier(0);
    if (st) { stage_slot(p, 0, kt + 2); stage_slot(p, 1, kt + 2); }
    if (kt == NKT - 2) asm volatile("s_waitcnt vmcnt(0)" ::: "memory");
    else               asm volatile("s_waitcnt vmcnt(6)" ::: "memory");
    __builtin_amdgcn_s_barrier();   // B3
    __builtin_amdgcn_sched_barrier(0);
  }

  #pragma unroll
  for (int m = 0; m < 4; ++m) {
    int row = row0 + wr*64 + m*16 + lk*4;
    #pragma unroll
    for (int n = 0; n < 4; ++n) {
      int col = col0 + wc*64 + n*16 + lr;
      #pragma unroll
      for (int j = 0; j < 4; ++j) {
        if (OBF) ((unsigned short*)Cv)[(size_t)(row + j) * N + col] = f2bf(acc[m][n][j]);
        else     ((float*)Cv)[(size_t)(row + j) * N + col] = acc[m][n][j];
      }
    }
  }
}

// ---------------- GLA phase A (MFMA): per-segment local state S^T in registers ------------
__global__ __launch_bounds__(256) void gla_phase_a(const unsigned short* __restrict__ qkb,
                                                   const unsigned short* __restrict__ vg,
                                                   const float* __restrict__ gk,
                                                   float* __restrict__ Sseg,
                                                   float* __restrict__ Dseg) {
  const int seg = blockIdx.x & 15;
  const int h   = (blockIdx.x >> 4) & 15;
  const int b   = blockIdx.x >> 8;
  const int t    = threadIdx.x;
  const int lane = t & 63;
  const int wid  = t >> 6;
  const int q    = lane >> 4;
  const int lr   = lane & 15;
  __shared__ float gc[16][68];
  __shared__ float dec_[64];
  __shared__ unsigned short kdT[64][40];   // [d][c], c>=16 zero
  __shared__ unsigned short vvT[128][40];  // [e][c], c>=16 zero

  for (int i = t; i < 1024; i += 256) kdT[i >> 4][16 + (i & 15)] = 0;
  for (int i = t; i < 2048; i += 256) vvT[i >> 4][16 + (i & 15)] = 0;

  f32x4 s_reg[2][4];
  #pragma unroll
  for (int et = 0; et < 2; ++et)
    #pragma unroll
    for (int dt = 0; dt < 4; ++dt) s_reg[et][dt] = (f32x4){0.f,0.f,0.f,0.f};
  float gt = 0.f;

  for (int c8 = 0; c8 < NCHUNK/NSEG; ++c8) {
    const int ch = seg * (NCHUNK/NSEG) + c8;
    __syncthreads();
    {
      float acc = 0.f;
      #pragma unroll
      for (int c = 0; c < CC; ++c) {
        acc += gk[((size_t)(b*T_ + ch*CC + c)) * 1024 + h*DK_ + lane];
        gc[c][lane] = acc;
      }
      gt += acc;
      dec_[lane] = expf(acc);
    }
    __syncthreads();
    {
      int c = t >> 4, d0 = (t & 15) * 4;
      ushort4 k4u = *reinterpret_cast<const ushort4*>(
          &qkb[((size_t)(b*T_ + ch*CC + c)) * 2048 + 1024 + h*DK_ + d0]);
      float ka[4] = {bf2f(k4u.x), bf2f(k4u.y), bf2f(k4u.z), bf2f(k4u.w)};
      #pragma unroll
      for (int j = 0; j < 4; ++j)
        kdT[d0 + j][c] = f2bf(ka[j] * expf(gc[CC-1][d0 + j] - gc[c][d0 + j]));
    }
    {
      int c = t & 15, e0 = (t >> 4) * 8;
      const ushort4* vp = reinterpret_cast<const ushort4*>(
          &vg[((size_t)(b*T_ + ch*CC + c)) * 4096 + h*DV_ + e0]);
      ushort4 a = vp[0], bb = vp[1];
      vvT[e0+0][c] = a.x;  vvT[e0+1][c] = a.y;  vvT[e0+2][c] = a.z;  vvT[e0+3][c] = a.w;
      vvT[e0+4][c] = bb.x; vvT[e0+5][c] = bb.y; vvT[e0+6][c] = bb.z; vvT[e0+7][c] = bb.w;
    }
    __syncthreads();
    bf16x8 vf[2], kf[4];
    #pragma unroll
    for (int et = 0; et < 2; ++et)
      vf[et] = *(const bf16x8*)&vvT[wid*32 + et*16 + lr][q*8];
    #pragma unroll
    for (int dt = 0; dt < 4; ++dt)
      kf[dt] = *(const bf16x8*)&kdT[dt*16 + lr][q*8];
    #pragma unroll
    for (int et = 0; et < 2; ++et)
      #pragma unroll
      for (int dt = 0; dt < 4; ++dt) {
        f32x4 dl = __builtin_amdgcn_mfma_f32_16x16x32_bf16(vf[et], kf[dt],
                     (f32x4){0.f,0.f,0.f,0.f}, 0, 0, 0);
        float dv = dec_[dt*16 + lr];
        #pragma unroll
        for (int j = 0; j < 4; ++j)
          s_reg[et][dt][j] = fmaf(s_reg[et][dt][j], dv, dl[j]);
      }
  }
  const size_t base = ((size_t)((b*H_ + h)*NSEG + seg)) * (DK_*DV_);
  #pragma unroll
  for (int et = 0; et < 2; ++et)
    #pragma unroll
    for (int dt = 0; dt < 4; ++dt)
      #pragma unroll
      for (int j = 0; j < 4; ++j)
        Sseg[base + (size_t)(wid*32 + et*16 + q*4 + j) * 64 + dt*16 + lr] = s_reg[et][dt][j];
  if (t < 64)
    Dseg[(size_t)((b*H_ + h)*NSEG + seg) * DK_ + t] = expf(gt);
}

// ---------------- GLA phase B: sequential combine over segments (Sseg is [e][d]) ----------
__global__ __launch_bounds__(256) void gla_combine(float* __restrict__ Sseg,
                                                   const float* __restrict__ Dseg) {
  const int bh = blockIdx.x;
  const int t = threadIdx.x;
  __shared__ float Dl[64];
  float4 S_run[8];
  #pragma unroll
  for (int j = 0; j < 8; ++j) S_run[j] = (float4){0.f,0.f,0.f,0.f};
  const int d0 = (t * 4) & 63;
  for (int seg = 0; seg < NSEG; ++seg) {
    const size_t base = ((size_t)bh*NSEG + seg) * (DK_*DV_);
    if (t < 64) Dl[t] = Dseg[((size_t)bh*NSEG + seg) * DK_ + t];
    __syncthreads();
    #pragma unroll
    for (int j = 0; j < 8; ++j) {
      int idx = j*1024 + t*4;
      float4 sl = *reinterpret_cast<float4*>(&Sseg[base + idx]);
      *reinterpret_cast<float4*>(&Sseg[base + idx]) = S_run[j];
      S_run[j].x = fmaf(Dl[d0+0], S_run[j].x, sl.x);
      S_run[j].y = fmaf(Dl[d0+1], S_run[j].y, sl.y);
      S_run[j].z = fmaf(Dl[d0+2], S_run[j].z, sl.z);
      S_run[j].w = fmaf(Dl[d0+3], S_run[j].w, sl.w);
    }
    __syncthreads();
  }
}

// ---------------- GLA phase C (MFMA): outputs + state march + fused RMSNorm/SiLU epilogue -
__global__ __launch_bounds__(256) void gla_phase_c(const unsigned short* __restrict__ qkb,
                                                   const unsigned short* __restrict__ vg,
                                                   const float* __restrict__ gk,
                                                   const float* __restrict__ Sseg,
                                                   const float* __restrict__ norm_w,
                                                   unsigned short* __restrict__ yb) {
  const int seg = blockIdx.x & 15;
  const int h   = (blockIdx.x >> 4) & 15;
  const int b   = blockIdx.x >> 8;
  const int t    = threadIdx.x;
  const int lane = t & 63;
  const int wid  = t >> 6;
  const int q    = lane >> 4;
  const int lr   = lane & 15;
  __shared__ float gc[16][68];
  __shared__ float dec_[64];
  __shared__ unsigned short qe[16][72];    // [c][d]
  __shared__ unsigned short ke[16][72];    // [m][d]
  __shared__ unsigned short kdT[64][40];   // [d][c], c>=16 zero
  __shared__ unsigned short vvT[128][40];  // [e][c], c>=16 zero
  __shared__ unsigned short Am[16][40];    // [c][m], m>=16 zero
  __shared__ unsigned short Sb[128][72];   // [e][d] bf16 shadow of S^T
  __shared__ float ss_lds[4][16];
  __shared__ float nw[128];

  for (int i = t; i < 1024; i += 256) kdT[i >> 4][16 + (i & 15)] = 0;
  for (int i = t; i < 2048; i += 256) vvT[i >> 4][16 + (i & 15)] = 0;
  if (t < 256) { int c = t >> 4, m = t & 15; Am[c][16 + m] = 0; }
  if (t < 128) nw[t] = norm_w[t];

  f32x4 s_reg[2][4];
  const size_t sbase = ((size_t)((b*H_ + h)*NSEG + seg)) * (DK_*DV_);
  #pragma unroll
  for (int et = 0; et < 2; ++et)
    #pragma unroll
    for (int dt = 0; dt < 4; ++dt)
      #pragma unroll
      for (int j = 0; j < 4; ++j) {
        int e = wid*32 + et*16 + q*4 + j, d = dt*16 + lr;
        float v = Sseg[sbase + (size_t)e * 64 + d];
        s_reg[et][dt][j] = v;
        Sb[e][d] = f2bf(v);
      }

  for (int c8 = 0; c8 < NCHUNK/NSEG; ++c8) {
    const int ch = seg * (NCHUNK/NSEG) + c8;
    __syncthreads();
    {
      float acc = 0.f;
      #pragma unroll
      for (int c = 0; c < CC; ++c) {
        acc += gk[((size_t)(b*T_ + ch*CC + c)) * 1024 + h*DK_ + lane];
        gc[c][lane] = acc;
      }
      dec_[lane] = expf(acc);
    }
    __syncthreads();
    {
      int c = t >> 4, d0 = (t & 15) * 4;
      const size_t gbq = ((size_t)(b*T_ + ch*CC + c)) * 2048 + h*DK_ + d0;
      ushort4 q4u = *reinterpret_cast<const ushort4*>(&qkb[gbq]);
      ushort4 k4u = *reinterpret_cast<const ushort4*>(&qkb[gbq + 1024]);
      float qa[4] = {bf2f(q4u.x), bf2f(q4u.y), bf2f(q4u.z), bf2f(q4u.w)};
      float ka[4] = {bf2f(k4u.x), bf2f(k4u.y), bf2f(k4u.z), bf2f(k4u.w)};
      ushort4 qw, kw;
      unsigned short* qwp = (unsigned short*)&qw;
      unsigned short* kwp = (unsigned short*)&kw;
      #pragma unroll
      for (int j = 0; j < 4; ++j) {
        float gcv = gc[c][d0 + j];
        float gl  = gc[CC-1][d0 + j];
        qwp[j] = f2bf(qa[j] * expf(gcv) * SCALE_);
        kwp[j] = f2bf(ka[j] * expf(-gcv));
        kdT[d0 + j][c] = f2bf(ka[j] * expf(gl - gcv));
      }
      *reinterpret_cast<ushort4*>(&qe[c][d0]) = qw;
      *reinterpret_cast<ushort4*>(&ke[c][d0]) = kw;
    }
    {
      int c = t & 15, e0 = (t >> 4) * 8;
      const ushort4* vp = reinterpret_cast<const ushort4*>(
          &vg[((size_t)(b*T_ + ch*CC + c)) * 4096 + h*DV_ + e0]);
      ushort4 a = vp[0], bb = vp[1];
      vvT[e0+0][c] = a.x;  vvT[e0+1][c] = a.y;  vvT[e0+2][c] = a.z;  vvT[e0+3][c] = a.w;
      vvT[e0+4][c] = bb.x; vvT[e0+5][c] = bb.y; vvT[e0+6][c] = bb.z; vvT[e0+7][c] = bb.w;
    }
    __syncthreads();
    bf16x8 qA0 = *(const bf16x8*)&qe[lr][q*8];
    bf16x8 qA1 = *(const bf16x8*)&qe[lr][32 + q*8];
    {
      bf16x8 kB0 = *(const bf16x8*)&ke[lr][q*8];
      bf16x8 kB1 = *(const bf16x8*)&ke[lr][32 + q*8];
      f32x4 accA = __builtin_amdgcn_mfma_f32_16x16x32_bf16(qA0, kB0,
                     (f32x4){0.f,0.f,0.f,0.f}, 0, 0, 0);
      accA = __builtin_amdgcn_mfma_f32_16x16x32_bf16(qA1, kB1, accA, 0, 0, 0);
      #pragma unroll
      for (int j = 0; j < 4; ++j) {
        int c = q*4 + j;
        Am[c][lr] = (lr <= c) ? f2bf(accA[j]) : (unsigned short)0;
      }
    }
    bf16x8 vf[2], kf[4];
    #pragma unroll
    for (int et = 0; et < 2; ++et)
      vf[et] = *(const bf16x8*)&vvT[wid*32 + et*16 + lr][q*8];
    #pragma unroll
    for (int dt = 0; dt < 4; ++dt)
      kf[dt] = *(const bf16x8*)&kdT[dt*16 + lr][q*8];
    #pragma unroll
    for (int et = 0; et < 2; ++et)
      #pragma unroll
      for (int dt = 0; dt < 4; ++dt) {
        f32x4 dl = __builtin_amdgcn_mfma_f32_16x16x32_bf16(vf[et], kf[dt],
                     (f32x4){0.f,0.f,0.f,0.f}, 0, 0, 0);
        float dv = dec_[dt*16 + lr];
        #pragma unroll
        for (int j = 0; j < 4; ++j)
          s_reg[et][dt][j] = fmaf(s_reg[et][dt][j], dv, dl[j]);
      }
    __syncthreads();
    {
      bf16x8 amA = *(const bf16x8*)&Am[lr][q*8];
      f32x4 accO[2];
      #pragma unroll
      for (int et = 0; et < 2; ++et) {
        int e0 = wid*32 + et*16;
        bf16x8 sB0 = *(const bf16x8*)&Sb[e0 + lr][q*8];
        bf16x8 sB1 = *(const bf16x8*)&Sb[e0 + lr][32 + q*8];
        accO[et] = __builtin_amdgcn_mfma_f32_16x16x32_bf16(qA0, sB0,
                     (f32x4){0.f,0.f,0.f,0.f}, 0, 0, 0);
        accO[et] = __builtin_amdgcn_mfma_f32_16x16x32_bf16(qA1, sB1, accO[et], 0, 0, 0);
        accO[et] = __builtin_amdgcn_mfma_f32_16x16x32_bf16(amA, vf[et], accO[et], 0, 0, 0);
      }
      #pragma unroll
      for (int j = 0; j < 4; ++j) {
        float pj = accO[0][j]*accO[0][j] + accO[1][j]*accO[1][j];
        pj += __shfl_xor(pj, 1, 64);
        pj += __shfl_xor(pj, 2, 64);
        pj += __shfl_xor(pj, 4, 64);
        pj += __shfl_xor(pj, 8, 64);
        if (lr == 0) ss_lds[wid][q*4 + j] = pj;
      }
      __syncthreads();
      #pragma unroll
      for (int j = 0; j < 4; ++j) {
        int r = q*4 + j;
        float tot = ss_lds[0][r] + ss_lds[1][r] + ss_lds[2][r] + ss_lds[3][r];
        float inv = rsqrtf(tot * (1.f/128.f) + 1e-5f);
        const size_t rowg = (size_t)(b*T_ + ch*CC + r);
        #pragma unroll
        for (int et = 0; et < 2; ++et) {
          int e = wid*32 + et*16 + lr;
          float gv = bf2f(vg[rowg * 4096 + 2048 + h*DV_ + e]);
          float si = gv / (1.f + expf(-gv));
          yb[rowg * 2048 + h*DV_ + e] = f2bf(accO[et][j] * inv * nw[e] * si);
        }
      }
    }
    __syncthreads();
    #pragma unroll
    for (int et = 0; et < 2; ++et)
      #pragma unroll
      for (int dt = 0; dt < 4; ++dt)
        #pragma unroll
        for (int j = 0; j < 4; ++j)
          Sb[wid*32 + et*16 + q*4 + j][dt*16 + lr] = f2bf(s_reg[et][dt][j]);
  }
}

// ------------------------------------------------------------------------------------------
extern "C" void kernel_launch(void* const* d_in, const int* in_sizes, int n_in,
                              void* d_out, int out_size, void* d_ws, size_t ws_size,
                              hipStream_t stream) {
  const float* x      = (const float*)d_in[0];
  const float* Wq     = (const float*)d_in[1];
  const float* Wk     = (const float*)d_in[2];
  const float* Wv     = (const float*)d_in[3];
  const float* Wg     = (const float*)d_in[4];
  const float* Wgk1   = (const float*)d_in[5];
  const float* Wgk2   = (const float*)d_in[6];
  const float* bgk2   = (const float*)d_in[7];
  const float* Wo     = (const float*)d_in[8];
  const float* norm_w = (const float*)d_in[9];
  float* out = (float*)d_out;
  float* ws  = (float*)d_ws;

  // ws layout (float-element offsets)
  unsigned short* qkb  = (unsigned short*)ws;              // bf16 [M][2048] q|k
  float*          gkb  = ws + 8388608;                     // f32 [M][1024]
  unsigned short* vg   = (unsigned short*)(ws + 12582912); // bf16 [M][4096] v|g
  float*          wbuf = ws + 20971520;                    // transient weights / yb region
  float*          Sseg = ws + 29360128;                    // f32 [B*H*NSEG][128e][64d]
  float*          Dseg = ws + 33554432;                    // 32768 f32
  unsigned short* WoT  = (unsigned short*)(ws + 33652736); // bf16 [2048][2048] (dedicated)

  // lifetime-disjoint aliases (stream order makes these safe)
  unsigned short* WqkT = (unsigned short*)wbuf;            // dead after qk GEMM
  unsigned short* WvgT = (unsigned short*)(wbuf + 2097152);// dead after vg GEMM
  unsigned short* xb   = (unsigned short*)(wbuf + 6291456);// bf16 [M][2048]; dead after GEMMs
  unsigned short* yb   = (unsigned short*)wbuf;            // phase_c output (WqkT/WvgT dead)

  dim3 blk(256);
  // lr gate (dispatched first, hidden under streaming) + convert x + weight transposes
  prep_kernel<<<dim3(7168), blk, 0, stream>>>(x, xb, Wq, Wk, Wv, Wg, Wo, WqkT, WvgT, WoT,
                                              Wgk1, Wgk2, bgk2, gkb);
  gemm256x128<true ><<<dim3(2048/128, 4096/256), dim3(512), 0, stream>>>(xb, WqkT, qkb, M_, 2048, HID_);
  gemm256<true     ><<<dim3(4096/256, 4096/256), dim3(512), 0, stream>>>(xb, WvgT, vg, M_, 4096, HID_);
  gla_phase_a<<<B_*H_*NSEG, blk, 0, stream>>>(qkb, vg, gkb, Sseg, Dseg);
  gla_combine<<<B_*H_, blk, 0, stream>>>(Sseg, Dseg);
  gla_phase_c<<<B_*H_*NSEG, blk, 0, stream>>>(qkb, vg, gkb, Sseg, norm_w, yb);
  gemm256x128<false><<<dim3(2048/128, 4096/256), dim3(512), 0, stream>>>(yb, WoT, out, M_, HID_, HID_);
}